// Round 13
// baseline (377.005 us; speedup 1.0000x reference)
//
#include <hip/hip_runtime.h>

#define BB 4
#define DD 4096
#define FF 128
#define SLOPE 0.2f

typedef float f32x4 __attribute__((ext_vector_type(4)));
typedef int   i32x4 __attribute__((ext_vector_type(4)));
typedef short bf16x8 __attribute__((ext_vector_type(8)));

__device__ __forceinline__ unsigned short f2bf(float v) {
  union { float f; unsigned u; } c; c.f = v;
  unsigned r = c.u + 0x7FFFu + ((c.u >> 16) & 1u);
  return (unsigned short)(r >> 16);
}

// Kernel A: Wh = x@W (f32 regs) -> WhT bf16 [B][F][D]; fs, ft (f32);
// mbpart[wg] = max(0, max over this wg's 64 rows of ft)  (no memset needed)
__global__ __launch_bounds__(256) void kA(
    const float* __restrict__ x, const float* __restrict__ W,
    const float* __restrict__ a_src, const float* __restrict__ a_tgt,
    unsigned short* __restrict__ WhT, float* __restrict__ fs,
    float* __restrict__ ft, float* __restrict__ mbpart)
{
  __shared__ __align__(16) float Ws[128 * 128];
  __shared__ __align__(16) float xs[64 * 128];     // reused as reduction scratch
  __shared__ unsigned short st[128 * 66];
  const int t = threadIdx.x;
  const int wg = blockIdx.x;            // 256 wgs x 64 rows
  const int row0 = wg * 64;             // flat row in [0, B*D)
  const int b = row0 / DD;
  const int i_in_b = row0 % DD;

  for (int i = t * 4; i < 128 * 128; i += 1024)
    *(float4*)&Ws[i] = *(const float4*)&W[i];
  for (int i = t * 4; i < 64 * 128; i += 1024)
    *(float4*)&xs[i] = *(const float4*)&x[(size_t)row0 * FF + i];
  __syncthreads();

  const int fg = t & 31, rg = t >> 5;
  const int f0 = fg * 4, r0 = rg * 8;
  float acc[8][4];
  #pragma unroll
  for (int a = 0; a < 8; ++a) acc[a][0] = acc[a][1] = acc[a][2] = acc[a][3] = 0.f;
  for (int k = 0; k < 128; ++k) {
    float4 wq = *(const float4*)&Ws[k * 128 + f0];
    #pragma unroll
    for (int rr = 0; rr < 8; ++rr) {
      float xv = xs[(r0 + rr) * 128 + k];
      acc[rr][0] += xv * wq.x; acc[rr][1] += xv * wq.y;
      acc[rr][2] += xv * wq.z; acc[rr][3] += xv * wq.w;
    }
  }
  __syncthreads();   // done reading xs; reuse as reduction scratch
  float* red_s = xs;             // [64][33]
  float* red_t = xs + 64 * 33;   // [64][33]
  float4 as4 = *(const float4*)&a_src[f0];
  float4 at4 = *(const float4*)&a_tgt[f0];
  #pragma unroll
  for (int rr = 0; rr < 8; ++rr) {
    float ps = acc[rr][0]*as4.x + acc[rr][1]*as4.y + acc[rr][2]*as4.z + acc[rr][3]*as4.w;
    float pt = acc[rr][0]*at4.x + acc[rr][1]*at4.y + acc[rr][2]*at4.z + acc[rr][3]*at4.w;
    red_s[(r0 + rr) * 33 + fg] = ps;
    red_t[(r0 + rr) * 33 + fg] = pt;
    st[(f0 + 0) * 66 + r0 + rr] = f2bf(acc[rr][0]);
    st[(f0 + 1) * 66 + r0 + rr] = f2bf(acc[rr][1]);
    st[(f0 + 2) * 66 + r0 + rr] = f2bf(acc[rr][2]);
    st[(f0 + 3) * 66 + r0 + rr] = f2bf(acc[rr][3]);
  }
  __syncthreads();
  if (t < 64) {
    float s = 0.f, tt = 0.f;
    #pragma unroll
    for (int q = 0; q < 32; ++q) { s += red_s[t * 33 + q]; tt += red_t[t * 33 + q]; }
    fs[row0 + t] = s;
    ft[row0 + t] = tt;
    float m = fmaxf(0.f, tt);
    #pragma unroll
    for (int s2 = 1; s2 < 64; s2 <<= 1) m = fmaxf(m, __shfl_xor(m, s2));
    if (t == 0) mbpart[wg] = m;        // unconditional write: no init required
  }
  // WhT bf16 writeout (coalesced per 64-wide row chunks)
  for (int p = 0; p < 32; ++p) {
    int idx = p * 256 + t;
    int f = idx >> 6, rl = idx & 63;
    WhT[((size_t)b * FF + f) * DD + i_in_b + rl] = st[f * 66 + rl];
  }
}

// Kernel F (fused, BARRIER-FREE): 64 rows/wg, 8 waves, 256 wgs.
// Each wave is fully independent: owns 8 rows end-to-end (adj stream, exp,
// attn store, AND PV for all 128 f via 8-row A-tiles with junk rows 8..15).
// p staging is a wave-local LDS round-trip (lgkmcnt fence, no s_barrier).
// B frags re-read per wave but L2-resident (1 MB/XCD working set).
__global__ __launch_bounds__(512, 2) void kF(
    const int* __restrict__ adj, const float* __restrict__ fs,
    const float* __restrict__ ft, const float* __restrict__ mbpart,
    const unsigned short* __restrict__ WhT, const float* __restrict__ bias,
    float* __restrict__ hout, float* __restrict__ attn)
{
  __shared__ __align__(16) unsigned short pbuf[2][8][8 * 256]; // 64 KB, per-wave 4KB regions
  __shared__ __align__(16) unsigned int mlds[64 * 128];        // 32 KB row bitmasks
  const int t = threadIdx.x;
  const int w = t >> 6, l = t & 63;
  const int hw = blockIdx.x;
  const int bid = (hw & 7) * 32 + (hw >> 3);   // bijective XCD swizzle (nwg=256)
  const int b = bid >> 6;
  const int i0 = (bid & 63) << 6;              // 64 rows per wg
  // per-batch ft upper bound from kA partials (wave-local reduce)
  float mbv = mbpart[b * 64 + l];
  #pragma unroll
  for (int s = 1; s < 64; s <<= 1) mbv = fmaxf(mbv, __shfl_xor(mbv, s));
  const int rbase = 8 * w;                     // wave owns rows rbase..rbase+7
  float fsr[8], Mr[8];
  #pragma unroll
  for (int m = 0; m < 8; ++m) {
    fsr[m] = fs[b * DD + i0 + rbase + m];
    Mr[m] = fmaxf(0.f, fsr[m] + mbv);
  }

  // ---- Pass 1: stream 8 adj rows in two 4-row groups, 2-deep pipelined ----
  const float* ftl = ft + (size_t)b * DD + l * 64;
  float sum[8];
  float inv[8];
  #pragma unroll
  for (int m = 0; m < 8; ++m) sum[m] = 0.f;

  #pragma unroll
  for (int g = 0; g < 2; ++g) {
    const int mb0 = g * 4;
    const int* ap[4];
    #pragma unroll
    for (int m = 0; m < 4; ++m)
      ap[m] = adj + (size_t)(b * DD + i0 + rbase + mb0 + m) * DD + l * 64;
    unsigned lo[4] = {0u, 0u, 0u, 0u}, hi[4] = {0u, 0u, 0u, 0u};

    auto p1_load = [&](i32x4 (&buf)[4][2], int q) {
      #pragma unroll
      for (int m = 0; m < 4; ++m) {
        buf[m][0] = *(const i32x4*)(ap[m] + q * 8);
        buf[m][1] = *(const i32x4*)(ap[m] + q * 8 + 4);
      }
    };
    auto p1_cons = [&](i32x4 (&buf)[4][2], int q) {
      #pragma unroll
      for (int u = 0; u < 2; ++u) {
        const int o = q * 8 + u * 4;
        float4 f = *(const float4*)(ftl + o);
        #pragma unroll
        for (int m = 0; m < 4; ++m) {
          i32x4 a = buf[m][u];
          float e;
          e = fsr[mb0+m] + f.x; e = e > 0.f ? e : SLOPE * e; e = a.x ? e : 0.f; sum[mb0+m] += __expf(e - Mr[mb0+m]);
          e = fsr[mb0+m] + f.y; e = e > 0.f ? e : SLOPE * e; e = a.y ? e : 0.f; sum[mb0+m] += __expf(e - Mr[mb0+m]);
          e = fsr[mb0+m] + f.z; e = e > 0.f ? e : SLOPE * e; e = a.z ? e : 0.f; sum[mb0+m] += __expf(e - Mr[mb0+m]);
          e = fsr[mb0+m] + f.w; e = e > 0.f ? e : SLOPE * e; e = a.w ? e : 0.f; sum[mb0+m] += __expf(e - Mr[mb0+m]);
          unsigned pack = (a.x ? 1u : 0u) | (a.y ? 2u : 0u) | (a.z ? 4u : 0u) | (a.w ? 8u : 0u);
          if (o < 32) lo[m] |= pack << o; else hi[m] |= pack << (o - 32);
        }
      }
    };

    i32x4 bA[4][2], bB[4][2];
    p1_load(bA, 0);
    p1_load(bB, 1);
    #pragma unroll
    for (int q = 0; q < 8; q += 2) {
      p1_cons(bA, q);
      if (q + 2 < 8) p1_load(bA, q + 2);
      p1_cons(bB, q + 1);
      if (q + 3 < 8) p1_load(bB, q + 3);
    }
    #pragma unroll
    for (int m = 0; m < 4; ++m) {
      uint2 mv; mv.x = lo[m]; mv.y = hi[m];
      *(uint2*)&mlds[(rbase + mb0 + m) * 128 + l * 2] = mv;
    }
  }
  #pragma unroll
  for (int m = 0; m < 8; ++m) {
    #pragma unroll
    for (int s = 1; s < 64; s <<= 1) sum[m] += __shfl_xor(sum[m], s);
    inv[m] = 1.0f / sum[m];
  }
  // wave-local fence: mlds writes visible to this wave's own reads below
  asm volatile("s_waitcnt lgkmcnt(0)" ::: "memory");

  // ---- Pass 2: barrier-free 16-chunk loop ----
  const float* ftb = ft + (size_t)b * DD;
  float* arow[8];
  unsigned pb_w[8], wb_[8];
  const int jl = l * 4;
  const unsigned mshift = (unsigned)(jl & 31);
  #pragma unroll
  for (int m = 0; m < 8; ++m) {
    const int r = rbase + m;
    arow[m] = attn + (size_t)b * DD * DD + (size_t)(i0 + r) * DD;
    pb_w[m] = (unsigned)m * 512u + (((unsigned)jl * 2u) ^ ((unsigned)m << 4));
    wb_[m] = (unsigned)r * 128u + (unsigned)(jl >> 5);
  }
  const int c15 = l & 15;
  const int arow_l = c15 & 7;                  // A row within wave's 8-row tile
  const int kg = l >> 4;
  const unsigned asw = (unsigned)arow_l << 4;
  // B pointers for the 8 f-tiles
  const unsigned short* wft[8];
  #pragma unroll
  for (int f8 = 0; f8 < 8; ++f8)
    wft[f8] = WhT + ((size_t)b * FF + f8 * 16 + c15) * DD + kg * 8;
  f32x4 acc[8];
  #pragma unroll
  for (int q = 0; q < 8; ++q) acc[q] = (f32x4){0.f, 0.f, 0.f, 0.f};

  bf16x8 Bu[2][4];
#define BLOAD(DST, C_, G_, U_) do { \
    _Pragma("unroll") \
    for (int q4 = 0; q4 < 4; ++q4) \
      DST[q4] = *(const bf16x8*)&wft[(G_) * 4 + q4][(size_t)(C_) * 256 + (U_) * 32]; \
  } while (0)

  BLOAD(Bu[0], 0, 0, 0);

  for (int c = 0; c < 16; ++c) {
    const int cb = c & 1;
    const int j = c * 256 + jl;
    // exp block for this wave's 8 rows (B loads for (c,0,0) in flight above)
    float4 f4 = *(const float4*)(ftb + j);
    #pragma unroll
    for (int m = 0; m < 8; ++m) {
      unsigned n = (mlds[wb_[m] + (unsigned)c * 8u] >> mshift) & 0xFu;
      float e, p0, p1, p2, p3;
      e = fsr[m] + f4.x; e = e > 0.f ? e : SLOPE * e; e = (n & 1u) ? e : 0.f; p0 = __expf(e - Mr[m]) * inv[m];
      e = fsr[m] + f4.y; e = e > 0.f ? e : SLOPE * e; e = (n & 2u) ? e : 0.f; p1 = __expf(e - Mr[m]) * inv[m];
      e = fsr[m] + f4.z; e = e > 0.f ? e : SLOPE * e; e = (n & 4u) ? e : 0.f; p2 = __expf(e - Mr[m]) * inv[m];
      e = fsr[m] + f4.w; e = e > 0.f ? e : SLOPE * e; e = (n & 8u) ? e : 0.f; p3 = __expf(e - Mr[m]) * inv[m];
      f32x4 v; v.x = p0; v.y = p1; v.z = p2; v.w = p3;
      *(f32x4*)(arow[m] + j) = v;
      ushort4 qv; qv.x = f2bf(p0); qv.y = f2bf(p1); qv.z = f2bf(p2); qv.w = f2bf(p3);
      *(ushort4*)((char*)&pbuf[cb][w][0] + pb_w[m]) = qv;
    }
    // wave-local fence: this wave's ds_writes done before its ds_reads below.
    // DS ops retire in order per wave; no s_barrier (waves fully independent).
    asm volatile("s_waitcnt lgkmcnt(0)" ::: "memory");
    #pragma unroll
    for (int g = 0; g < 2; ++g) {
      #pragma unroll
      for (int u = 0; u < 8; ++u) {
        if (u < 7)       { BLOAD(Bu[(u + 1) & 1], c, g, u + 1); }
        else if (g == 0) { BLOAD(Bu[0], c, 1, 0); }
        else             { BLOAD(Bu[0], c + 1, 0, 0); }  // c=15: benign read into ws tail
        unsigned ao = (unsigned)arow_l * 512u + ((((unsigned)u * 64u) + (unsigned)kg * 16u) ^ asw);
        bf16x8 A = *(const bf16x8*)((const char*)&pbuf[cb][w][0] + ao);
        #pragma unroll
        for (int q4 = 0; q4 < 4; ++q4)
          acc[g * 4 + q4] = __builtin_amdgcn_mfma_f32_16x16x32_bf16(A, Bu[u & 1][q4], acc[g * 4 + q4], 0, 0, 0);
      }
    }
  }
#undef BLOAD

  // Epilogue: C rows 0..7 are real (A rows 8..15 were junk); lanes kg<2 store.
  if (kg < 2) {
    #pragma unroll
    for (int f8 = 0; f8 < 8; ++f8) {
      const float bv = bias[f8 * 16 + c15];
      #pragma unroll
      for (int q = 0; q < 4; ++q) {
        int orow = kg * 4 + q;               // C/D: row = (lane>>4)*4 + reg
        hout[((size_t)b * DD + i0 + rbase + orow) * FF + f8 * 16 + c15] = acc[f8][q] + bv;
      }
    }
  }
}

extern "C" void kernel_launch(void* const* d_in, const int* in_sizes, int n_in,
                              void* d_out, int out_size, void* d_ws, size_t ws_size,
                              hipStream_t stream) {
  const float* x     = (const float*)d_in[0];
  const int*   adj   = (const int*)d_in[1];
  const float* W     = (const float*)d_in[2];
  const float* a_src = (const float*)d_in[3];
  const float* a_tgt = (const float*)d_in[4];
  const float* bias  = (const float*)d_in[5];
  char* ws = (char*)d_ws;
  unsigned short* WhT    = (unsigned short*)ws;         // 4 MB
  float*        fs     = (float*)(ws + 4194304);        // 64 KB
  float*        ft     = (float*)(ws + 4259840);        // 64 KB
  float*        mbpart = (float*)(ws + 4325376);        // 1 KB
  float* hout = (float*)d_out;                          // [B][D][F]
  float* attn = hout + (size_t)BB * DD * FF;            // [B][D][D]
  kA<<<256, 256, 0, stream>>>(x, W, a_src, a_tgt, WhT, fs, ft, mbpart);
  kF<<<256, 512, 0, stream>>>(adj, fs, ft, mbpart, WhT, bias, hout, attn);
}

// Round 14
// 351.366 us; speedup vs baseline: 1.0730x; 1.0730x over previous
//
#include <hip/hip_runtime.h>

#define BB 4
#define DD 4096
#define FF 128
#define SLOPE 0.2f

typedef float f32x4 __attribute__((ext_vector_type(4)));
typedef int   i32x4 __attribute__((ext_vector_type(4)));
typedef short bf16x8 __attribute__((ext_vector_type(8)));

// LDS-only barrier: ds_writes visible across waves, but global loads/stores
// stay in flight (no vmcnt drain, unlike __syncthreads()).
#define SOFT_BARRIER() do { \
  asm volatile("s_waitcnt lgkmcnt(0)" ::: "memory"); \
  __builtin_amdgcn_s_barrier(); \
} while (0)

__device__ __forceinline__ unsigned short f2bf(float v) {
  union { float f; unsigned u; } c; c.f = v;
  unsigned r = c.u + 0x7FFFu + ((c.u >> 16) & 1u);
  return (unsigned short)(r >> 16);
}

// Kernel A: Wh = x@W (f32 regs) -> WhT bf16 [B][F][D]; fs, ft (f32);
// mbpart[wg] = max(0, max over this wg's 64 rows of ft)  (no memset needed)
__global__ __launch_bounds__(256) void kA(
    const float* __restrict__ x, const float* __restrict__ W,
    const float* __restrict__ a_src, const float* __restrict__ a_tgt,
    unsigned short* __restrict__ WhT, float* __restrict__ fs,
    float* __restrict__ ft, float* __restrict__ mbpart)
{
  __shared__ __align__(16) float Ws[128 * 128];
  __shared__ __align__(16) float xs[64 * 128];     // reused as reduction scratch
  __shared__ unsigned short st[128 * 66];
  const int t = threadIdx.x;
  const int wg = blockIdx.x;            // 256 wgs x 64 rows
  const int row0 = wg * 64;             // flat row in [0, B*D)
  const int b = row0 / DD;
  const int i_in_b = row0 % DD;

  for (int i = t * 4; i < 128 * 128; i += 1024)
    *(float4*)&Ws[i] = *(const float4*)&W[i];
  for (int i = t * 4; i < 64 * 128; i += 1024)
    *(float4*)&xs[i] = *(const float4*)&x[(size_t)row0 * FF + i];
  __syncthreads();

  const int fg = t & 31, rg = t >> 5;
  const int f0 = fg * 4, r0 = rg * 8;
  float acc[8][4];
  #pragma unroll
  for (int a = 0; a < 8; ++a) acc[a][0] = acc[a][1] = acc[a][2] = acc[a][3] = 0.f;
  for (int k = 0; k < 128; ++k) {
    float4 wq = *(const float4*)&Ws[k * 128 + f0];
    #pragma unroll
    for (int rr = 0; rr < 8; ++rr) {
      float xv = xs[(r0 + rr) * 128 + k];
      acc[rr][0] += xv * wq.x; acc[rr][1] += xv * wq.y;
      acc[rr][2] += xv * wq.z; acc[rr][3] += xv * wq.w;
    }
  }
  __syncthreads();   // done reading xs; reuse as reduction scratch
  float* red_s = xs;             // [64][33]
  float* red_t = xs + 64 * 33;   // [64][33]
  float4 as4 = *(const float4*)&a_src[f0];
  float4 at4 = *(const float4*)&a_tgt[f0];
  #pragma unroll
  for (int rr = 0; rr < 8; ++rr) {
    float ps = acc[rr][0]*as4.x + acc[rr][1]*as4.y + acc[rr][2]*as4.z + acc[rr][3]*as4.w;
    float pt = acc[rr][0]*at4.x + acc[rr][1]*at4.y + acc[rr][2]*at4.z + acc[rr][3]*at4.w;
    red_s[(r0 + rr) * 33 + fg] = ps;
    red_t[(r0 + rr) * 33 + fg] = pt;
    st[(f0 + 0) * 66 + r0 + rr] = f2bf(acc[rr][0]);
    st[(f0 + 1) * 66 + r0 + rr] = f2bf(acc[rr][1]);
    st[(f0 + 2) * 66 + r0 + rr] = f2bf(acc[rr][2]);
    st[(f0 + 3) * 66 + r0 + rr] = f2bf(acc[rr][3]);
  }
  __syncthreads();
  if (t < 64) {
    float s = 0.f, tt = 0.f;
    #pragma unroll
    for (int q = 0; q < 32; ++q) { s += red_s[t * 33 + q]; tt += red_t[t * 33 + q]; }
    fs[row0 + t] = s;
    ft[row0 + t] = tt;
    float m = fmaxf(0.f, tt);
    #pragma unroll
    for (int s2 = 1; s2 < 64; s2 <<= 1) m = fmaxf(m, __shfl_xor(m, s2));
    if (t == 0) mbpart[wg] = m;        // unconditional write: no init required
  }
  // WhT bf16 writeout (coalesced per 64-wide row chunks)
  for (int p = 0; p < 32; ++p) {
    int idx = p * 256 + t;
    int f = idx >> 6, rl = idx & 63;
    WhT[((size_t)b * FF + f) * DD + i_in_b + rl] = st[f * 66 + rl];
  }
}

// Kernel F (fused, wave-specialized): 64 rows/wg, 16 waves, 256 wgs (1 wg/CU).
// Pass 1: all 16 waves stream 4 adj rows each -> mlds bitmasks + sums_l.
// Pass 2: waves 8..15 PRODUCE (exp + attn store + p_lds[cb] write, 8 rows each);
//         waves 0..7 CONSUME (R10's MFMA split: f-tile x 4 row-tiles, shared B).
// Double-buffered p_lds; matched soft barriers; producer chunk c+1 overlaps
// consumer chunk c on each SIMD (2 producers + 2 consumers resident).
__global__ __launch_bounds__(1024, 4) void kF(
    const int* __restrict__ adj, const float* __restrict__ fs,
    const float* __restrict__ ft, const float* __restrict__ mbpart,
    const unsigned short* __restrict__ WhT, const float* __restrict__ bias,
    float* __restrict__ hout, float* __restrict__ attn)
{
  __shared__ __align__(16) unsigned short p_lds[2][64 * 256];  // 64 KB
  __shared__ __align__(16) unsigned int mlds[64 * 128];        // 32 KB
  __shared__ float sums_l[64];
  const int t = threadIdx.x;
  const int w = t >> 6, l = t & 63;            // w in 0..15
  const int hw = blockIdx.x;
  const int bid = (hw & 7) * 32 + (hw >> 3);   // bijective XCD swizzle (nwg=256)
  const int b = bid >> 6;
  const int i0 = (bid & 63) << 6;              // 64 rows per wg
  // per-batch ft upper bound from kA partials
  float mbv = mbpart[b * 64 + l];
  #pragma unroll
  for (int s = 1; s < 64; s <<= 1) mbv = fmaxf(mbv, __shfl_xor(mbv, s));

  // ---- Pass 1: wave w streams rows 4w..4w+3 (2-deep pipelined) ----
  {
    const int rb1 = 4 * w;
    float fsr1[4], Mr1[4];
    #pragma unroll
    for (int m = 0; m < 4; ++m) {
      fsr1[m] = fs[b * DD + i0 + rb1 + m];
      Mr1[m] = fmaxf(0.f, fsr1[m] + mbv);
    }
    const int* ap[4];
    #pragma unroll
    for (int m = 0; m < 4; ++m)
      ap[m] = adj + (size_t)(b * DD + i0 + rb1 + m) * DD + l * 64;
    const float* ftl = ft + (size_t)b * DD + l * 64;
    float sum[4] = {0.f, 0.f, 0.f, 0.f};
    unsigned lo[4] = {0u, 0u, 0u, 0u}, hi[4] = {0u, 0u, 0u, 0u};

    auto p1_load = [&](i32x4 (&buf)[4][2], int q) {
      #pragma unroll
      for (int m = 0; m < 4; ++m) {
        buf[m][0] = *(const i32x4*)(ap[m] + q * 8);
        buf[m][1] = *(const i32x4*)(ap[m] + q * 8 + 4);
      }
    };
    auto p1_cons = [&](i32x4 (&buf)[4][2], int q) {
      #pragma unroll
      for (int u = 0; u < 2; ++u) {
        const int o = q * 8 + u * 4;
        float4 f = *(const float4*)(ftl + o);
        #pragma unroll
        for (int m = 0; m < 4; ++m) {
          i32x4 a = buf[m][u];
          float e;
          e = fsr1[m] + f.x; e = e > 0.f ? e : SLOPE * e; e = a.x ? e : 0.f; sum[m] += __expf(e - Mr1[m]);
          e = fsr1[m] + f.y; e = e > 0.f ? e : SLOPE * e; e = a.y ? e : 0.f; sum[m] += __expf(e - Mr1[m]);
          e = fsr1[m] + f.z; e = e > 0.f ? e : SLOPE * e; e = a.z ? e : 0.f; sum[m] += __expf(e - Mr1[m]);
          e = fsr1[m] + f.w; e = e > 0.f ? e : SLOPE * e; e = a.w ? e : 0.f; sum[m] += __expf(e - Mr1[m]);
          unsigned pack = (a.x ? 1u : 0u) | (a.y ? 2u : 0u) | (a.z ? 4u : 0u) | (a.w ? 8u : 0u);
          if (o < 32) lo[m] |= pack << o; else hi[m] |= pack << (o - 32);
        }
      }
    };

    i32x4 bA[4][2], bB[4][2];
    p1_load(bA, 0);
    p1_load(bB, 1);
    #pragma unroll
    for (int q = 0; q < 8; q += 2) {
      p1_cons(bA, q);
      if (q + 2 < 8) p1_load(bA, q + 2);
      p1_cons(bB, q + 1);
      if (q + 3 < 8) p1_load(bB, q + 3);
    }
    #pragma unroll
    for (int m = 0; m < 4; ++m) {
      uint2 mv; mv.x = lo[m]; mv.y = hi[m];
      *(uint2*)&mlds[(rb1 + m) * 128 + l * 2] = mv;
    }
    #pragma unroll
    for (int m = 0; m < 4; ++m) {
      #pragma unroll
      for (int s = 1; s < 64; s <<= 1) sum[m] += __shfl_xor(sum[m], s);
      if (l == 0) sums_l[rb1 + m] = sum[m];
    }
  }
  SOFT_BARRIER();   // [A] masks + sums visible to all waves

  if (w >= 8) {
    // ================= PRODUCER (waves 8..15): rows 8pw..8pw+7 =================
    const int pw = w - 8;
    const int rbase = 8 * pw;
    float fsr[8], Mr[8], inv[8];
    #pragma unroll
    for (int m = 0; m < 8; ++m) {
      fsr[m] = fs[b * DD + i0 + rbase + m];
      Mr[m] = fmaxf(0.f, fsr[m] + mbv);
      inv[m] = 1.0f / sums_l[rbase + m];
    }
    const float* ftb = ft + (size_t)b * DD;
    float* arow[8];
    unsigned o_[8], wb_[8];
    const int jl = l * 4;
    const unsigned mshift = (unsigned)(jl & 31);
    #pragma unroll
    for (int m = 0; m < 8; ++m) {
      const int r = rbase + m;
      arow[m] = attn + (size_t)b * DD * DD + (size_t)(i0 + r) * DD;
      o_[m] = (((unsigned)r * 512u) + (unsigned)jl * 2u) ^ ((unsigned)(r & 7) << 4);
      wb_[m] = (unsigned)r * 128u + (unsigned)(jl >> 5);
    }
    float4 fA, fB;
    fA = *(const float4*)(ftb + jl);

#define PRODUCE(CC, FCUR, FNXT) do { \
    const int c_ = (CC); \
    const int j_ = c_ * 256 + jl; \
    FNXT = *(const float4*)(ftb + ((((c_) + 1) & 15) * 256 + jl)); \
    float4 f4_ = FCUR; \
    unsigned short* pb_ = (unsigned short*)&p_lds[c_ & 1][0]; \
    _Pragma("unroll") \
    for (int m = 0; m < 8; ++m) { \
      unsigned n_ = (mlds[wb_[m] + (unsigned)c_ * 8u] >> mshift) & 0xFu; \
      float e_, p0_, p1_, p2_, p3_; \
      e_ = fsr[m] + f4_.x; e_ = e_ > 0.f ? e_ : SLOPE * e_; e_ = (n_ & 1u) ? e_ : 0.f; p0_ = __expf(e_ - Mr[m]) * inv[m]; \
      e_ = fsr[m] + f4_.y; e_ = e_ > 0.f ? e_ : SLOPE * e_; e_ = (n_ & 2u) ? e_ : 0.f; p1_ = __expf(e_ - Mr[m]) * inv[m]; \
      e_ = fsr[m] + f4_.z; e_ = e_ > 0.f ? e_ : SLOPE * e_; e_ = (n_ & 4u) ? e_ : 0.f; p2_ = __expf(e_ - Mr[m]) * inv[m]; \
      e_ = fsr[m] + f4_.w; e_ = e_ > 0.f ? e_ : SLOPE * e_; e_ = (n_ & 8u) ? e_ : 0.f; p3_ = __expf(e_ - Mr[m]) * inv[m]; \
      f32x4 v_; v_.x = p0_; v_.y = p1_; v_.z = p2_; v_.w = p3_; \
      *(f32x4*)(arow[m] + j_) = v_; \
      ushort4 qv_; qv_.x = f2bf(p0_); qv_.y = f2bf(p1_); qv_.z = f2bf(p2_); qv_.w = f2bf(p3_); \
      *(ushort4*)((char*)pb_ + o_[m]) = qv_; \
    } \
  } while (0)

    PRODUCE(0, fA, fB);
    SOFT_BARRIER();   // #0: chunk 0 ready
    #pragma unroll 1
    for (int cc = 0; cc < 8; ++cc) {
      PRODUCE(2 * cc + 1, fB, fA);
      SOFT_BARRIER();
      if (cc < 7) PRODUCE(2 * cc + 2, fA, fB);
      SOFT_BARRIER();
    }
#undef PRODUCE
  } else {
    // ================= CONSUMER (waves 0..7): f-tile f0 = 16w =================
    const int f0 = w * 16;
    const int c15 = l & 15;
    const int kg = l >> 4;
    const unsigned abase = (unsigned)c15 * 512u + (unsigned)kg * 16u;
    const unsigned asw = (unsigned)(c15 & 7) << 4;
    const unsigned short* wrow = WhT + ((size_t)b * FF + f0 + c15) * DD + kg * 8;
    f32x4 acc[4];
    #pragma unroll
    for (int q = 0; q < 4; ++q) acc[q] = (f32x4){0.f, 0.f, 0.f, 0.f};

    bf16x8 BvA[8], BvB[8];
    #pragma unroll
    for (int u = 0; u < 8; ++u)
      BvA[u] = *(const bf16x8*)&wrow[(size_t)u * 32];
    SOFT_BARRIER();   // #0: chunk 0 ready

#define CONSUME(CC, BCUR, BNXT) do { \
    const int c_ = (CC); \
    _Pragma("unroll") \
    for (int u = 0; u < 8; ++u) \
      BNXT[u] = *(const bf16x8*)&wrow[(size_t)((((c_) + 1) & 15) * 8 + u) * 32]; \
    const char* pb_ = (const char*)&p_lds[c_ & 1][0]; \
    _Pragma("unroll") \
    for (int u = 0; u < 8; ++u) { \
      unsigned ao_ = (abase + (unsigned)u * 64u) ^ asw; \
      _Pragma("unroll") \
      for (int T = 0; T < 4; ++T) { \
        bf16x8 A_ = *(const bf16x8*)(pb_ + ao_ + (unsigned)T * 8192u); \
        acc[T] = __builtin_amdgcn_mfma_f32_16x16x32_bf16(A_, BCUR[u], acc[T], 0, 0, 0); \
      } \
    } \
  } while (0)

    #pragma unroll 1
    for (int cc = 0; cc < 8; ++cc) {
      CONSUME(2 * cc, BvA, BvB);
      SOFT_BARRIER();
      CONSUME(2 * cc + 1, BvB, BvA);
      SOFT_BARRIER();
    }
#undef CONSUME

    const float bv = bias[f0 + c15];
    #pragma unroll
    for (int T = 0; T < 4; ++T) {
      #pragma unroll
      for (int q = 0; q < 4; ++q) {
        int orow = T * 16 + kg * 4 + q;   // C/D: row = (lane>>4)*4 + reg
        hout[((size_t)b * DD + i0 + orow) * FF + f0 + c15] = acc[T][q] + bv;
      }
    }
  }
}

extern "C" void kernel_launch(void* const* d_in, const int* in_sizes, int n_in,
                              void* d_out, int out_size, void* d_ws, size_t ws_size,
                              hipStream_t stream) {
  const float* x     = (const float*)d_in[0];
  const int*   adj   = (const int*)d_in[1];
  const float* W     = (const float*)d_in[2];
  const float* a_src = (const float*)d_in[3];
  const float* a_tgt = (const float*)d_in[4];
  const float* bias  = (const float*)d_in[5];
  char* ws = (char*)d_ws;
  unsigned short* WhT    = (unsigned short*)ws;         // 4 MB
  float*        fs     = (float*)(ws + 4194304);        // 64 KB
  float*        ft     = (float*)(ws + 4259840);        // 64 KB
  float*        mbpart = (float*)(ws + 4325376);        // 1 KB
  float* hout = (float*)d_out;                          // [B][D][F]
  float* attn = hout + (size_t)BB * DD * FF;            // [B][D][D]
  kA<<<256, 256, 0, stream>>>(x, W, a_src, a_tgt, WhT, fs, ft, mbpart);
  kF<<<256, 1024, 0, stream>>>(adj, fs, ft, mbpart, WhT, bias, hout, attn);
}

// Round 15
// 259.605 us; speedup vs baseline: 1.4522x; 1.3535x over previous
//
#include <hip/hip_runtime.h>

#define BB 4
#define DD 4096
#define FF 128
#define SLOPE 0.2f

typedef float f32x4 __attribute__((ext_vector_type(4)));
typedef int   i32x4 __attribute__((ext_vector_type(4)));
typedef short bf16x8 __attribute__((ext_vector_type(8)));

#define SOFT_BARRIER() do { \
  asm volatile("s_waitcnt lgkmcnt(0)" ::: "memory"); \
  __builtin_amdgcn_s_barrier(); \
} while (0)

__device__ __forceinline__ unsigned short f2bf(float v) {
  union { float f; unsigned u; } c; c.f = v;
  unsigned r = c.u + 0x7FFFu + ((c.u >> 16) & 1u);
  return (unsigned short)(r >> 16);
}

// Kernel A: Wh = x@W (f32 regs) -> WhT bf16 [B][F][D]; fs, ft (f32);
// mbpart[wg] = max(0, max over this wg's 64 rows of ft)  (no memset needed)
__global__ __launch_bounds__(256) void kA(
    const float* __restrict__ x, const float* __restrict__ W,
    const float* __restrict__ a_src, const float* __restrict__ a_tgt,
    unsigned short* __restrict__ WhT, float* __restrict__ fs,
    float* __restrict__ ft, float* __restrict__ mbpart)
{
  __shared__ __align__(16) float Ws[128 * 128];
  __shared__ __align__(16) float xs[64 * 128];     // reused as reduction scratch
  __shared__ unsigned short st[128 * 66];
  const int t = threadIdx.x;
  const int wg = blockIdx.x;            // 256 wgs x 64 rows
  const int row0 = wg * 64;             // flat row in [0, B*D)
  const int b = row0 / DD;
  const int i_in_b = row0 % DD;

  for (int i = t * 4; i < 128 * 128; i += 1024)
    *(float4*)&Ws[i] = *(const float4*)&W[i];
  for (int i = t * 4; i < 64 * 128; i += 1024)
    *(float4*)&xs[i] = *(const float4*)&x[(size_t)row0 * FF + i];
  __syncthreads();

  const int fg = t & 31, rg = t >> 5;
  const int f0 = fg * 4, r0 = rg * 8;
  float acc[8][4];
  #pragma unroll
  for (int a = 0; a < 8; ++a) acc[a][0] = acc[a][1] = acc[a][2] = acc[a][3] = 0.f;
  for (int k = 0; k < 128; ++k) {
    float4 wq = *(const float4*)&Ws[k * 128 + f0];
    #pragma unroll
    for (int rr = 0; rr < 8; ++rr) {
      float xv = xs[(r0 + rr) * 128 + k];
      acc[rr][0] += xv * wq.x; acc[rr][1] += xv * wq.y;
      acc[rr][2] += xv * wq.z; acc[rr][3] += xv * wq.w;
    }
  }
  __syncthreads();   // done reading xs; reuse as reduction scratch
  float* red_s = xs;             // [64][33]
  float* red_t = xs + 64 * 33;   // [64][33]
  float4 as4 = *(const float4*)&a_src[f0];
  float4 at4 = *(const float4*)&a_tgt[f0];
  #pragma unroll
  for (int rr = 0; rr < 8; ++rr) {
    float ps = acc[rr][0]*as4.x + acc[rr][1]*as4.y + acc[rr][2]*as4.z + acc[rr][3]*as4.w;
    float pt = acc[rr][0]*at4.x + acc[rr][1]*at4.y + acc[rr][2]*at4.z + acc[rr][3]*at4.w;
    red_s[(r0 + rr) * 33 + fg] = ps;
    red_t[(r0 + rr) * 33 + fg] = pt;
    st[(f0 + 0) * 66 + r0 + rr] = f2bf(acc[rr][0]);
    st[(f0 + 1) * 66 + r0 + rr] = f2bf(acc[rr][1]);
    st[(f0 + 2) * 66 + r0 + rr] = f2bf(acc[rr][2]);
    st[(f0 + 3) * 66 + r0 + rr] = f2bf(acc[rr][3]);
  }
  __syncthreads();
  if (t < 64) {
    float s = 0.f, tt = 0.f;
    #pragma unroll
    for (int q = 0; q < 32; ++q) { s += red_s[t * 33 + q]; tt += red_t[t * 33 + q]; }
    fs[row0 + t] = s;
    ft[row0 + t] = tt;
    float m = fmaxf(0.f, tt);
    #pragma unroll
    for (int s2 = 1; s2 < 64; s2 <<= 1) m = fmaxf(m, __shfl_xor(m, s2));
    if (t == 0) mbpart[wg] = m;        // unconditional write: no init required
  }
  // WhT bf16 writeout (coalesced per 64-wide row chunks)
  for (int p = 0; p < 32; ++p) {
    int idx = p * 256 + t;
    int f = idx >> 6, rl = idx & 63;
    WhT[((size_t)b * FF + f) * DD + i_in_b + rl] = st[f * 66 + rl];
  }
}

// Kernel P1: one wave per row, pure streaming, no LDS/barriers.
// Streams adj once -> 1-bit mask [row][128 words] + rowsum of exp(e - M).
__global__ __launch_bounds__(256) void kP1(
    const int* __restrict__ adj, const float* __restrict__ fs,
    const float* __restrict__ ft, const float* __restrict__ mbpart,
    unsigned int* __restrict__ maskw, float* __restrict__ sums)
{
  const int t = threadIdx.x;
  const int wv = t >> 6, l = t & 63;
  const int row = blockIdx.x * 4 + wv;       // flat row in [0, B*D)
  const int b = row >> 12;
  float mbv = mbpart[b * 64 + l];
  #pragma unroll
  for (int s = 1; s < 64; s <<= 1) mbv = fmaxf(mbv, __shfl_xor(mbv, s));
  const float fsr = fs[row];
  const float M = fmaxf(0.f, fsr + mbv);
  const int* arow = adj + (size_t)row * DD + l * 64;
  const float* ftl = ft + (size_t)b * DD + l * 64;
  float sum = 0.f;
  unsigned wlo = 0u, whi = 0u;
  #pragma unroll
  for (int q = 0; q < 4; ++q) {
    unsigned bits = 0u;
    #pragma unroll
    for (int u = 0; u < 4; ++u) {
      const int o = q * 16 + u * 4;
      i32x4 a = *(const i32x4*)(arow + o);
      float4 f = *(const float4*)(ftl + o);
      float e0 = fsr + f.x; e0 = e0 > 0.f ? e0 : SLOPE * e0; e0 = a.x ? e0 : 0.f;
      float e1 = fsr + f.y; e1 = e1 > 0.f ? e1 : SLOPE * e1; e1 = a.y ? e1 : 0.f;
      float e2 = fsr + f.z; e2 = e2 > 0.f ? e2 : SLOPE * e2; e2 = a.z ? e2 : 0.f;
      float e3 = fsr + f.w; e3 = e3 > 0.f ? e3 : SLOPE * e3; e3 = a.w ? e3 : 0.f;
      sum += __expf(e0 - M) + __expf(e1 - M) + __expf(e2 - M) + __expf(e3 - M);
      bits |= (a.x ? 1u : 0u) << (u * 4 + 0);
      bits |= (a.y ? 1u : 0u) << (u * 4 + 1);
      bits |= (a.z ? 1u : 0u) << (u * 4 + 2);
      bits |= (a.w ? 1u : 0u) << (u * 4 + 3);
    }
    if      (q == 0) wlo  = bits;
    else if (q == 1) wlo |= bits << 16;
    else if (q == 2) whi  = bits;
    else             whi |= bits << 16;
  }
  uint2 mv; mv.x = wlo; mv.y = whi;
  *(uint2*)(maskw + (size_t)row * 128 + l * 2) = mv;
  #pragma unroll
  for (int s = 1; s < 64; s <<= 1) sum += __shfl_xor(sum, s);
  if (l == 0) sums[row] = sum;
}

// Kernel P2: 32 rows/wg, 8 waves, 512 wgs -> 2 wg/CU (48 KB LDS).
// No adj stream: masks from kP1 (staged 16 KB), sums from kP1.
// R10's chunk pipeline: B/ft double-buffered, soft barrier, MFMA (2 row-tiles).
__global__ __launch_bounds__(512, 4) void kP2(
    const unsigned int* __restrict__ maskw, const float* __restrict__ fs,
    const float* __restrict__ ft, const float* __restrict__ mbpart,
    const float* __restrict__ sums, const unsigned short* __restrict__ WhT,
    const float* __restrict__ bias, float* __restrict__ hout,
    float* __restrict__ attn)
{
  __shared__ __align__(16) unsigned short p_lds[2][32 * 256];  // 32 KB, XOR-swizzled
  __shared__ __align__(16) unsigned int mlds[32 * 128];        // 16 KB row bitmasks
  const int t = threadIdx.x;
  const int w = t >> 6, l = t & 63;
  const int hw = blockIdx.x;
  const int bid = (hw & 7) * 64 + (hw >> 3);   // bijective XCD swizzle (nwg=512)
  const int b = bid >> 7;
  const int i0 = (bid & 127) << 5;             // 32 rows per wg
  // stage masks for rows i0..i0+31 (coalesced 16 KB)
  {
    const unsigned int* msrc = maskw + (size_t)(b * DD + i0) * 128;
    *(uint4*)&mlds[t * 8]     = *(const uint4*)&msrc[t * 8];
    *(uint4*)&mlds[t * 8 + 4] = *(const uint4*)&msrc[t * 8 + 4];
  }
  float mbv = mbpart[b * 64 + l];
  #pragma unroll
  for (int s = 1; s < 64; s <<= 1) mbv = fmaxf(mbv, __shfl_xor(mbv, s));
  const int rbase = 4 * w;                     // wave's rows (local 0..31)
  float fsr[4], Mr[4], inv[4];
  #pragma unroll
  for (int m = 0; m < 4; ++m) {
    fsr[m] = fs[b * DD + i0 + rbase + m];
    Mr[m] = fmaxf(0.f, fsr[m] + mbv);
    inv[m] = 1.0f / sums[b * DD + i0 + rbase + m];
  }

  const float* ftb = ft + (size_t)b * DD;
  float* arow[4];
  unsigned o_[4], wb_[4];
  const int jl = l * 4;
  const unsigned mshift = (unsigned)(jl & 31);
  #pragma unroll
  for (int m = 0; m < 4; ++m) {
    const int r = rbase + m;
    arow[m] = attn + (size_t)b * DD * DD + (size_t)(i0 + r) * DD;
    o_[m] = (((unsigned)r * 512u) + (unsigned)jl * 2u) ^ ((unsigned)(r & 7) << 4);
    wb_[m] = (unsigned)r * 128u + (unsigned)(jl >> 5);
  }
  const int f0 = w * 16;
  const int c15 = l & 15;
  const int kg = l >> 4;
  const unsigned abase = (unsigned)c15 * 512u + (unsigned)kg * 16u;
  const unsigned asw = (unsigned)(c15 & 7) << 4;
  const unsigned short* wrow = WhT + ((size_t)b * FF + f0 + c15) * DD + kg * 8;
  f32x4 acc[2];
  acc[0] = (f32x4){0.f, 0.f, 0.f, 0.f};
  acc[1] = (f32x4){0.f, 0.f, 0.f, 0.f};

  bf16x8 BvA[8], BvB[8];
  float4 fA, fB;
  #pragma unroll
  for (int u = 0; u < 8; ++u)
    BvA[u] = *(const bf16x8*)&wrow[(size_t)u * 32];
  fA = *(const float4*)(ftb + jl);
  SOFT_BARRIER();   // mask staging visible

#define CHUNK_BODY(CC, BCUR, BNXT, FCUR, FNXT) do { \
    const int c_ = (CC); \
    const int j_ = c_ * 256 + jl; \
    _Pragma("unroll") \
    for (int u = 0; u < 8; ++u) \
      BNXT[u] = *(const bf16x8*)&wrow[(size_t)((((c_) + 1) & 15) * 8 + u) * 32]; \
    FNXT = *(const float4*)(ftb + ((((c_) + 1) & 15) * 256 + jl)); \
    float4 f4_ = FCUR; \
    unsigned short* pb_ = (unsigned short*)&p_lds[c_ & 1][0]; \
    _Pragma("unroll") \
    for (int m = 0; m < 4; ++m) { \
      unsigned n_ = (mlds[wb_[m] + (unsigned)c_ * 8u] >> mshift) & 0xFu; \
      float e_, p0_, p1_, p2_, p3_; \
      e_ = fsr[m] + f4_.x; e_ = e_ > 0.f ? e_ : SLOPE * e_; e_ = (n_ & 1u) ? e_ : 0.f; p0_ = __expf(e_ - Mr[m]) * inv[m]; \
      e_ = fsr[m] + f4_.y; e_ = e_ > 0.f ? e_ : SLOPE * e_; e_ = (n_ & 2u) ? e_ : 0.f; p1_ = __expf(e_ - Mr[m]) * inv[m]; \
      e_ = fsr[m] + f4_.z; e_ = e_ > 0.f ? e_ : SLOPE * e_; e_ = (n_ & 4u) ? e_ : 0.f; p2_ = __expf(e_ - Mr[m]) * inv[m]; \
      e_ = fsr[m] + f4_.w; e_ = e_ > 0.f ? e_ : SLOPE * e_; e_ = (n_ & 8u) ? e_ : 0.f; p3_ = __expf(e_ - Mr[m]) * inv[m]; \
      f32x4 v_; v_.x = p0_; v_.y = p1_; v_.z = p2_; v_.w = p3_; \
      *(f32x4*)(arow[m] + j_) = v_; \
      ushort4 qv_; qv_.x = f2bf(p0_); qv_.y = f2bf(p1_); qv_.z = f2bf(p2_); qv_.w = f2bf(p3_); \
      *(ushort4*)((char*)pb_ + o_[m]) = qv_; \
    } \
    SOFT_BARRIER(); \
    const char* pr_ = (const char*)&p_lds[c_ & 1][0]; \
    _Pragma("unroll") \
    for (int u = 0; u < 8; ++u) { \
      unsigned ao_ = (abase + (unsigned)u * 64u) ^ asw; \
      bf16x8 A0_ = *(const bf16x8*)(pr_ + ao_); \
      bf16x8 A1_ = *(const bf16x8*)(pr_ + ao_ + 8192u); \
      acc[0] = __builtin_amdgcn_mfma_f32_16x16x32_bf16(A0_, BCUR[u], acc[0], 0, 0, 0); \
      acc[1] = __builtin_amdgcn_mfma_f32_16x16x32_bf16(A1_, BCUR[u], acc[1], 0, 0, 0); \
    } \
  } while (0)

  for (int cc = 0; cc < 8; ++cc) {
    CHUNK_BODY(cc * 2,     BvA, BvB, fA, fB);
    CHUNK_BODY(cc * 2 + 1, BvB, BvA, fB, fA);
  }
#undef CHUNK_BODY

  const float bv = bias[f0 + c15];
  #pragma unroll
  for (int T = 0; T < 2; ++T) {
    #pragma unroll
    for (int q = 0; q < 4; ++q) {
      int orow = T * 16 + kg * 4 + q;   // C/D: row = (lane>>4)*4 + reg
      hout[((size_t)b * DD + i0 + orow) * FF + f0 + c15] = acc[T][q] + bv;
    }
  }
}

extern "C" void kernel_launch(void* const* d_in, const int* in_sizes, int n_in,
                              void* d_out, int out_size, void* d_ws, size_t ws_size,
                              hipStream_t stream) {
  const float* x     = (const float*)d_in[0];
  const int*   adj   = (const int*)d_in[1];
  const float* W     = (const float*)d_in[2];
  const float* a_src = (const float*)d_in[3];
  const float* a_tgt = (const float*)d_in[4];
  const float* bias  = (const float*)d_in[5];
  char* ws = (char*)d_ws;
  unsigned short* WhT    = (unsigned short*)ws;          // 4 MB
  float*        fs     = (float*)(ws + 4194304);         // 64 KB
  float*        ft     = (float*)(ws + 4259840);         // 64 KB
  float*        mbpart = (float*)(ws + 4325376);         // 1 KB
  unsigned int* maskw  = (unsigned int*)(ws + 4456448);  // 8 MB
  float*        sums   = (float*)(ws + 12845056);        // 64 KB
  float* hout = (float*)d_out;                           // [B][D][F]
  float* attn = hout + (size_t)BB * DD * FF;             // [B][D][D]
  kA<<<256, 256, 0, stream>>>(x, W, a_src, a_tgt, WhT, fs, ft, mbpart);
  kP1<<<BB * DD / 4, 256, 0, stream>>>(adj, fs, ft, mbpart, maskw, sums);
  kP2<<<512, 512, 0, stream>>>(maskw, fs, ft, mbpart, sums, WhT, bias, hout, attn);
}

// Round 16
// 225.418 us; speedup vs baseline: 1.6725x; 1.1517x over previous
//
#include <hip/hip_runtime.h>

#define BB 4
#define DD 4096
#define FF 128
#define SLOPE 0.2f

typedef float f32x4 __attribute__((ext_vector_type(4)));
typedef int   i32x4 __attribute__((ext_vector_type(4)));
typedef short bf16x8 __attribute__((ext_vector_type(8)));

// LDS-only barrier: ds_writes visible across waves, but global loads/stores
// stay in flight (no vmcnt drain, unlike __syncthreads()).
#define SOFT_BARRIER() do { \
  asm volatile("s_waitcnt lgkmcnt(0)" ::: "memory"); \
  __builtin_amdgcn_s_barrier(); \
} while (0)

__device__ __forceinline__ unsigned short f2bf(float v) {
  union { float f; unsigned u; } c; c.f = v;
  unsigned r = c.u + 0x7FFFu + ((c.u >> 16) & 1u);
  return (unsigned short)(r >> 16);
}

// Kernel A: Wh = x@W (f32 regs) -> WhT bf16 [B][F][D]; fs, ft (f32);
// mbpart[wg] = max(0, max over this wg's 64 rows of ft)  (no memset needed)
__global__ __launch_bounds__(256) void kA(
    const float* __restrict__ x, const float* __restrict__ W,
    const float* __restrict__ a_src, const float* __restrict__ a_tgt,
    unsigned short* __restrict__ WhT, float* __restrict__ fs,
    float* __restrict__ ft, float* __restrict__ mbpart)
{
  __shared__ __align__(16) float Ws[128 * 128];
  __shared__ __align__(16) float xs[64 * 128];     // reused as reduction scratch
  __shared__ unsigned short st[128 * 66];
  const int t = threadIdx.x;
  const int wg = blockIdx.x;            // 256 wgs x 64 rows
  const int row0 = wg * 64;             // flat row in [0, B*D)
  const int b = row0 / DD;
  const int i_in_b = row0 % DD;

  for (int i = t * 4; i < 128 * 128; i += 1024)
    *(float4*)&Ws[i] = *(const float4*)&W[i];
  for (int i = t * 4; i < 64 * 128; i += 1024)
    *(float4*)&xs[i] = *(const float4*)&x[(size_t)row0 * FF + i];
  __syncthreads();

  const int fg = t & 31, rg = t >> 5;
  const int f0 = fg * 4, r0 = rg * 8;
  float acc[8][4];
  #pragma unroll
  for (int a = 0; a < 8; ++a) acc[a][0] = acc[a][1] = acc[a][2] = acc[a][3] = 0.f;
  for (int k = 0; k < 128; ++k) {
    float4 wq = *(const float4*)&Ws[k * 128 + f0];
    #pragma unroll
    for (int rr = 0; rr < 8; ++rr) {
      float xv = xs[(r0 + rr) * 128 + k];
      acc[rr][0] += xv * wq.x; acc[rr][1] += xv * wq.y;
      acc[rr][2] += xv * wq.z; acc[rr][3] += xv * wq.w;
    }
  }
  __syncthreads();   // done reading xs; reuse as reduction scratch
  float* red_s = xs;             // [64][33]
  float* red_t = xs + 64 * 33;   // [64][33]
  float4 as4 = *(const float4*)&a_src[f0];
  float4 at4 = *(const float4*)&a_tgt[f0];
  #pragma unroll
  for (int rr = 0; rr < 8; ++rr) {
    float ps = acc[rr][0]*as4.x + acc[rr][1]*as4.y + acc[rr][2]*as4.z + acc[rr][3]*as4.w;
    float pt = acc[rr][0]*at4.x + acc[rr][1]*at4.y + acc[rr][2]*at4.z + acc[rr][3]*at4.w;
    red_s[(r0 + rr) * 33 + fg] = ps;
    red_t[(r0 + rr) * 33 + fg] = pt;
    st[(f0 + 0) * 66 + r0 + rr] = f2bf(acc[rr][0]);
    st[(f0 + 1) * 66 + r0 + rr] = f2bf(acc[rr][1]);
    st[(f0 + 2) * 66 + r0 + rr] = f2bf(acc[rr][2]);
    st[(f0 + 3) * 66 + r0 + rr] = f2bf(acc[rr][3]);
  }
  __syncthreads();
  if (t < 64) {
    float s = 0.f, tt = 0.f;
    #pragma unroll
    for (int q = 0; q < 32; ++q) { s += red_s[t * 33 + q]; tt += red_t[t * 33 + q]; }
    fs[row0 + t] = s;
    ft[row0 + t] = tt;
    float m = fmaxf(0.f, tt);
    #pragma unroll
    for (int s2 = 1; s2 < 64; s2 <<= 1) m = fmaxf(m, __shfl_xor(m, s2));
    if (t == 0) mbpart[wg] = m;        // unconditional write: no init required
  }
  // WhT bf16 writeout (coalesced per 64-wide row chunks)
  for (int p = 0; p < 32; ++p) {
    int idx = p * 256 + t;
    int f = idx >> 6, rl = idx & 63;
    WhT[((size_t)b * FF + f) * DD + i_in_b + rl] = st[f * 66 + rl];
  }
}

// Kernel F (fused): 64 rows/wg, 8 waves, 256 wgs (R10 structure, CHUNK=512).
// 8 chunks of 512 cols -> 8 barriers (half of R10). Masks live in REGISTERS
// (lo8/hi8 per lane from pass 1), fetched per-chunk via 2 shfls + select:
// no mlds -> LDS = 2x64KB p_lds only. B reloads placed after last use
// (half-chunk groups) so loads span exp+barrier windows.
__global__ __launch_bounds__(512, 2) void kF(
    const int* __restrict__ adj, const float* __restrict__ fs,
    const float* __restrict__ ft, const float* __restrict__ mbpart,
    const unsigned short* __restrict__ WhT, const float* __restrict__ bias,
    float* __restrict__ hout, float* __restrict__ attn)
{
  __shared__ __align__(16) unsigned short p_lds[2][64 * 512];  // 128 KB, XOR-swizzled
  const int t = threadIdx.x;
  const int w = t >> 6, l = t & 63;
  const int hw = blockIdx.x;
  const int bid = (hw & 7) * 32 + (hw >> 3);   // bijective XCD swizzle (nwg=256)
  const int b = bid >> 6;
  const int i0 = (bid & 63) << 6;              // 64 rows per wg
  // per-batch ft upper bound from kA partials
  float mbv = mbpart[b * 64 + l];
  #pragma unroll
  for (int s = 1; s < 64; s <<= 1) mbv = fmaxf(mbv, __shfl_xor(mbv, s));
  const int rbase = 8 * w;                     // wave owns rows rbase..rbase+7
  float fsr[8], Mr[8];
  #pragma unroll
  for (int m = 0; m < 8; ++m) {
    fsr[m] = fs[b * DD + i0 + rbase + m];
    Mr[m] = fmaxf(0.f, fsr[m] + mbv);
  }

  // ---- Pass 1: stream 8 adj rows (two 4-row groups, 2-deep pipelined).
  //      Masks stay in registers lo8/hi8 (lane l owns cols l*64..l*64+63). ----
  const float* ftl = ft + (size_t)b * DD + l * 64;
  float sum[8];
  float inv[8];
  unsigned lo8[8], hi8[8];
  #pragma unroll
  for (int m = 0; m < 8; ++m) sum[m] = 0.f;

  #pragma unroll
  for (int g = 0; g < 2; ++g) {
    const int mb0 = g * 4;
    const int* ap[4];
    #pragma unroll
    for (int m = 0; m < 4; ++m)
      ap[m] = adj + (size_t)(b * DD + i0 + rbase + mb0 + m) * DD + l * 64;
    unsigned lo[4] = {0u, 0u, 0u, 0u}, hi[4] = {0u, 0u, 0u, 0u};

    auto p1_load = [&](i32x4 (&buf)[4][2], int q) {
      #pragma unroll
      for (int m = 0; m < 4; ++m) {
        buf[m][0] = *(const i32x4*)(ap[m] + q * 8);
        buf[m][1] = *(const i32x4*)(ap[m] + q * 8 + 4);
      }
    };
    auto p1_cons = [&](i32x4 (&buf)[4][2], int q) {
      #pragma unroll
      for (int u = 0; u < 2; ++u) {
        const int o = q * 8 + u * 4;
        float4 f = *(const float4*)(ftl + o);
        #pragma unroll
        for (int m = 0; m < 4; ++m) {
          i32x4 a = buf[m][u];
          float e;
          e = fsr[mb0+m] + f.x; e = e > 0.f ? e : SLOPE * e; e = a.x ? e : 0.f; sum[mb0+m] += __expf(e - Mr[mb0+m]);
          e = fsr[mb0+m] + f.y; e = e > 0.f ? e : SLOPE * e; e = a.y ? e : 0.f; sum[mb0+m] += __expf(e - Mr[mb0+m]);
          e = fsr[mb0+m] + f.z; e = e > 0.f ? e : SLOPE * e; e = a.z ? e : 0.f; sum[mb0+m] += __expf(e - Mr[mb0+m]);
          e = fsr[mb0+m] + f.w; e = e > 0.f ? e : SLOPE * e; e = a.w ? e : 0.f; sum[mb0+m] += __expf(e - Mr[mb0+m]);
          unsigned pack = (a.x ? 1u : 0u) | (a.y ? 2u : 0u) | (a.z ? 4u : 0u) | (a.w ? 8u : 0u);
          if (o < 32) lo[m] |= pack << o; else hi[m] |= pack << (o - 32);
        }
      }
    };

    i32x4 bA[4][2], bB[4][2];
    p1_load(bA, 0);
    p1_load(bB, 1);
    #pragma unroll
    for (int q = 0; q < 8; q += 2) {
      p1_cons(bA, q);
      if (q + 2 < 8) p1_load(bA, q + 2);
      p1_cons(bB, q + 1);
      if (q + 3 < 8) p1_load(bB, q + 3);
    }
    #pragma unroll
    for (int m = 0; m < 4; ++m) { lo8[mb0 + m] = lo[m]; hi8[mb0 + m] = hi[m]; }
  }
  #pragma unroll
  for (int m = 0; m < 8; ++m) {
    #pragma unroll
    for (int s = 1; s < 64; s <<= 1) sum[m] += __shfl_xor(sum[m], s);
    inv[m] = 1.0f / sum[m];
  }

  // ---- Pass 2: 8 chunks x 512 cols (soft barrier per chunk) ----
  const float* ftb = ft + (size_t)b * DD;
  float* arow[8];
  unsigned pw_[8];
  const int jl = l * 4;
  const unsigned mshift = (unsigned)(l & 7) * 4;   // bit offset within lo/hi word
  const bool mlow = (l & 15) < 8;                  // use lo vs hi
  #pragma unroll
  for (int m = 0; m < 8; ++m) {
    const int r = rbase + m;
    arow[m] = attn + (size_t)b * DD * DD + (size_t)(i0 + r) * DD;
    pw_[m] = (unsigned)r * 1024u + (((unsigned)jl * 2u) ^ ((unsigned)(r & 7) << 4));
  }
  const int f0 = w * 16;
  const int c15 = l & 15;
  const int kg = l >> 4;
  const unsigned abase = (unsigned)c15 * 1024u + (unsigned)kg * 16u;
  const unsigned asw = (unsigned)(c15 & 7) << 4;
  const unsigned short* wrow = WhT + ((size_t)b * FF + f0 + c15) * DD + kg * 8;
  f32x4 acc[4];
  #pragma unroll
  for (int q = 0; q < 4; ++q) acc[q] = (f32x4){0.f, 0.f, 0.f, 0.f};

  bf16x8 Bv0[8], Bv1[8];        // half-chunk B buffers (u 0..7 / 8..15)
  float4 fA0, fA1, fB0, fB1;    // ft double-buffer (two sub-blocks per chunk)
  #pragma unroll
  for (int u = 0; u < 8; ++u) {
    Bv0[u] = *(const bf16x8*)&wrow[(size_t)u * 32];
    Bv1[u] = *(const bf16x8*)&wrow[(size_t)(8 + u) * 32];
  }
  fA0 = *(const float4*)(ftb + jl);
  fA1 = *(const float4*)(ftb + 256 + jl);

#define CHUNK_BODY(CC, FC0, FC1, FN0, FN1) do { \
    const int c_ = (CC); \
    const int cn_ = (c_ + 1) & 7; \
    FN0 = *(const float4*)(ftb + cn_ * 512 + jl); \
    FN1 = *(const float4*)(ftb + cn_ * 512 + 256 + jl); \
    unsigned short* pb_ = (unsigned short*)&p_lds[c_ & 1][0]; \
    _Pragma("unroll") \
    for (int s_ = 0; s_ < 2; ++s_) { \
      float4 f4_ = s_ ? FC1 : FC0; \
      const int j_ = c_ * 512 + s_ * 256 + jl; \
      const int src_ = c_ * 8 + s_ * 4 + (l >> 4); \
      const unsigned poff_ = (unsigned)s_ * 512u; \
      _Pragma("unroll") \
      for (int m = 0; m < 8; ++m) { \
        unsigned wl_ = __shfl(lo8[m], src_); \
        unsigned wh_ = __shfl(hi8[m], src_); \
        unsigned n_ = ((mlow ? wl_ : wh_) >> mshift) & 0xFu; \
        float e_, p0_, p1_, p2_, p3_; \
        e_ = fsr[m] + f4_.x; e_ = e_ > 0.f ? e_ : SLOPE * e_; e_ = (n_ & 1u) ? e_ : 0.f; p0_ = __expf(e_ - Mr[m]) * inv[m]; \
        e_ = fsr[m] + f4_.y; e_ = e_ > 0.f ? e_ : SLOPE * e_; e_ = (n_ & 2u) ? e_ : 0.f; p1_ = __expf(e_ - Mr[m]) * inv[m]; \
        e_ = fsr[m] + f4_.z; e_ = e_ > 0.f ? e_ : SLOPE * e_; e_ = (n_ & 4u) ? e_ : 0.f; p2_ = __expf(e_ - Mr[m]) * inv[m]; \
        e_ = fsr[m] + f4_.w; e_ = e_ > 0.f ? e_ : SLOPE * e_; e_ = (n_ & 8u) ? e_ : 0.f; p3_ = __expf(e_ - Mr[m]) * inv[m]; \
        f32x4 v_; v_.x = p0_; v_.y = p1_; v_.z = p2_; v_.w = p3_; \
        *(f32x4*)(arow[m] + j_) = v_; \
        ushort4 qv_; qv_.x = f2bf(p0_); qv_.y = f2bf(p1_); qv_.z = f2bf(p2_); qv_.w = f2bf(p3_); \
        *(ushort4*)((char*)pb_ + pw_[m] + poff_) = qv_; \
      } \
    } \
    SOFT_BARRIER(); \
    const char* pr_ = (const char*)&p_lds[c_ & 1][0]; \
    _Pragma("unroll") \
    for (int u = 0; u < 8; ++u) { \
      unsigned ao_ = (abase + (unsigned)u * 64u) ^ asw; \
      _Pragma("unroll") \
      for (int T = 0; T < 4; ++T) { \
        bf16x8 A_ = *(const bf16x8*)(pr_ + ao_ + (unsigned)T * 16384u); \
        acc[T] = __builtin_amdgcn_mfma_f32_16x16x32_bf16(A_, Bv0[u], acc[T], 0, 0, 0); \
      } \
    } \
    _Pragma("unroll") \
    for (int u = 0; u < 8; ++u) \
      Bv0[u] = *(const bf16x8*)&wrow[(size_t)(cn_ * 16 + u) * 32]; \
    _Pragma("unroll") \
    for (int u = 0; u < 8; ++u) { \
      unsigned ao_ = (abase + (unsigned)(8 + u) * 64u) ^ asw; \
      _Pragma("unroll") \
      for (int T = 0; T < 4; ++T) { \
        bf16x8 A_ = *(const bf16x8*)(pr_ + ao_ + (unsigned)T * 16384u); \
        acc[T] = __builtin_amdgcn_mfma_f32_16x16x32_bf16(A_, Bv1[u], acc[T], 0, 0, 0); \
      } \
    } \
    _Pragma("unroll") \
    for (int u = 0; u < 8; ++u) \
      Bv1[u] = *(const bf16x8*)&wrow[(size_t)(cn_ * 16 + 8 + u) * 32]; \
  } while (0)

  for (int cc = 0; cc < 4; ++cc) {
    CHUNK_BODY(cc * 2,     fA0, fA1, fB0, fB1);
    CHUNK_BODY(cc * 2 + 1, fB0, fB1, fA0, fA1);
  }
#undef CHUNK_BODY

  const float bv = bias[f0 + c15];
  #pragma unroll
  for (int T = 0; T < 4; ++T) {
    #pragma unroll
    for (int q = 0; q < 4; ++q) {
      int orow = T * 16 + kg * 4 + q;   // C/D: row = (lane>>4)*4 + reg
      hout[((size_t)b * DD + i0 + orow) * FF + f0 + c15] = acc[T][q] + bv;
    }
  }
}

extern "C" void kernel_launch(void* const* d_in, const int* in_sizes, int n_in,
                              void* d_out, int out_size, void* d_ws, size_t ws_size,
                              hipStream_t stream) {
  const float* x     = (const float*)d_in[0];
  const int*   adj   = (const int*)d_in[1];
  const float* W     = (const float*)d_in[2];
  const float* a_src = (const float*)d_in[3];
  const float* a_tgt = (const float*)d_in[4];
  const float* bias  = (const float*)d_in[5];
  char* ws = (char*)d_ws;
  unsigned short* WhT    = (unsigned short*)ws;         // 4 MB
  float*        fs     = (float*)(ws + 4194304);        // 64 KB
  float*        ft     = (float*)(ws + 4259840);        // 64 KB
  float*        mbpart = (float*)(ws + 4325376);        // 1 KB
  float* hout = (float*)d_out;                          // [B][D][F]
  float* attn = hout + (size_t)BB * DD * FF;            // [B][D][D]
  kA<<<256, 256, 0, stream>>>(x, W, a_src, a_tgt, WhT, fs, ft, mbpart);
  kF<<<256, 512, 0, stream>>>(adj, fs, ft, mbpart, WhT, bias, hout, attn);
}

// Round 17
// 200.330 us; speedup vs baseline: 1.8819x; 1.1252x over previous
//
#include <hip/hip_runtime.h>

#define BB 4
#define DD 4096
#define FF 128
#define SLOPE 0.2f

typedef float f32x4 __attribute__((ext_vector_type(4)));
typedef int   i32x4 __attribute__((ext_vector_type(4)));
typedef short bf16x8 __attribute__((ext_vector_type(8)));

// LDS-only barrier: ds_writes visible across waves, but global loads/stores
// stay in flight (no vmcnt drain, unlike __syncthreads()).
#define SOFT_BARRIER() do { \
  asm volatile("s_waitcnt lgkmcnt(0)" ::: "memory"); \
  __builtin_amdgcn_s_barrier(); \
} while (0)

__device__ __forceinline__ unsigned short f2bf(float v) {
  union { float f; unsigned u; } c; c.f = v;
  unsigned r = c.u + 0x7FFFu + ((c.u >> 16) & 1u);
  return (unsigned short)(r >> 16);
}

// Kernel A: Wh = x@W (f32 regs) -> WhT bf16 [B][F][D]; fs, ft (f32);
// mbpart[wg] = max(0, max over this wg's 64 rows of ft)  (no memset needed)
__global__ __launch_bounds__(256) void kA(
    const float* __restrict__ x, const float* __restrict__ W,
    const float* __restrict__ a_src, const float* __restrict__ a_tgt,
    unsigned short* __restrict__ WhT, float* __restrict__ fs,
    float* __restrict__ ft, float* __restrict__ mbpart)
{
  __shared__ __align__(16) float Ws[128 * 128];
  __shared__ __align__(16) float xs[64 * 128];     // reused as reduction scratch
  __shared__ unsigned short st[128 * 66];
  const int t = threadIdx.x;
  const int wg = blockIdx.x;            // 256 wgs x 64 rows
  const int row0 = wg * 64;             // flat row in [0, B*D)
  const int b = row0 / DD;
  const int i_in_b = row0 % DD;

  for (int i = t * 4; i < 128 * 128; i += 1024)
    *(float4*)&Ws[i] = *(const float4*)&W[i];
  for (int i = t * 4; i < 64 * 128; i += 1024)
    *(float4*)&xs[i] = *(const float4*)&x[(size_t)row0 * FF + i];
  __syncthreads();

  const int fg = t & 31, rg = t >> 5;
  const int f0 = fg * 4, r0 = rg * 8;
  float acc[8][4];
  #pragma unroll
  for (int a = 0; a < 8; ++a) acc[a][0] = acc[a][1] = acc[a][2] = acc[a][3] = 0.f;
  for (int k = 0; k < 128; ++k) {
    float4 wq = *(const float4*)&Ws[k * 128 + f0];
    #pragma unroll
    for (int rr = 0; rr < 8; ++rr) {
      float xv = xs[(r0 + rr) * 128 + k];
      acc[rr][0] += xv * wq.x; acc[rr][1] += xv * wq.y;
      acc[rr][2] += xv * wq.z; acc[rr][3] += xv * wq.w;
    }
  }
  __syncthreads();   // done reading xs; reuse as reduction scratch
  float* red_s = xs;             // [64][33]
  float* red_t = xs + 64 * 33;   // [64][33]
  float4 as4 = *(const float4*)&a_src[f0];
  float4 at4 = *(const float4*)&a_tgt[f0];
  #pragma unroll
  for (int rr = 0; rr < 8; ++rr) {
    float ps = acc[rr][0]*as4.x + acc[rr][1]*as4.y + acc[rr][2]*as4.z + acc[rr][3]*as4.w;
    float pt = acc[rr][0]*at4.x + acc[rr][1]*at4.y + acc[rr][2]*at4.z + acc[rr][3]*at4.w;
    red_s[(r0 + rr) * 33 + fg] = ps;
    red_t[(r0 + rr) * 33 + fg] = pt;
    st[(f0 + 0) * 66 + r0 + rr] = f2bf(acc[rr][0]);
    st[(f0 + 1) * 66 + r0 + rr] = f2bf(acc[rr][1]);
    st[(f0 + 2) * 66 + r0 + rr] = f2bf(acc[rr][2]);
    st[(f0 + 3) * 66 + r0 + rr] = f2bf(acc[rr][3]);
  }
  __syncthreads();
  if (t < 64) {
    float s = 0.f, tt = 0.f;
    #pragma unroll
    for (int q = 0; q < 32; ++q) { s += red_s[t * 33 + q]; tt += red_t[t * 33 + q]; }
    fs[row0 + t] = s;
    ft[row0 + t] = tt;
    float m = fmaxf(0.f, tt);
    #pragma unroll
    for (int s2 = 1; s2 < 64; s2 <<= 1) m = fmaxf(m, __shfl_xor(m, s2));
    if (t == 0) mbpart[wg] = m;        // unconditional write: no init required
  }
  // WhT bf16 writeout (coalesced per 64-wide row chunks)
  for (int p = 0; p < 32; ++p) {
    int idx = p * 256 + t;
    int f = idx >> 6, rl = idx & 63;
    WhT[((size_t)b * FF + f) * DD + i_in_b + rl] = st[f * 66 + rl];
  }
}

// Kernel F (fused): exact R10 structure (64 rows/wg, 8 waves, 256 wgs,
// 16-chunk pipeline, B/ft double-buffer, soft barrier) + 3 micro-opts:
//  (1) leaky_relu via fmaxf(e, SLOPE*e)   — fewer VALU on exp path
//  (2) attn stores AFTER the barrier      — off the barrier-gating path,
//      overlap the MFMA section (v_[8] f32x4 live across barrier)
//  (3) s_setprio(1) around MFMA cluster   — favor MFMA-phase waves
__global__ __launch_bounds__(512, 2) void kF(
    const int* __restrict__ adj, const float* __restrict__ fs,
    const float* __restrict__ ft, const float* __restrict__ mbpart,
    const unsigned short* __restrict__ WhT, const float* __restrict__ bias,
    float* __restrict__ hout, float* __restrict__ attn)
{
  __shared__ __align__(16) unsigned short p_lds[2][64 * 256];  // 64 KB, XOR-swizzled
  __shared__ __align__(16) unsigned int mlds[64 * 128];        // 32 KB row bitmasks
  const int t = threadIdx.x;
  const int w = t >> 6, l = t & 63;
  const int hw = blockIdx.x;
  const int bid = (hw & 7) * 32 + (hw >> 3);   // bijective XCD swizzle (nwg=256)
  const int b = bid >> 6;
  const int i0 = (bid & 63) << 6;              // 64 rows per wg
  // per-batch ft upper bound from kA partials
  float mbv = mbpart[b * 64 + l];
  #pragma unroll
  for (int s = 1; s < 64; s <<= 1) mbv = fmaxf(mbv, __shfl_xor(mbv, s));
  const int rbase = 8 * w;                     // wave owns rows rbase..rbase+7
  float fsr[8], Mr[8];
  #pragma unroll
  for (int m = 0; m < 8; ++m) {
    fsr[m] = fs[b * DD + i0 + rbase + m];
    Mr[m] = fmaxf(0.f, fsr[m] + mbv);
  }

  // ---- Pass 1: stream 8 adj rows in two 4-row groups, 2-deep pipelined ----
  const float* ftl = ft + (size_t)b * DD + l * 64;
  float sum[8];
  float inv[8];
  #pragma unroll
  for (int m = 0; m < 8; ++m) sum[m] = 0.f;

  #pragma unroll
  for (int g = 0; g < 2; ++g) {
    const int mb0 = g * 4;
    const int* ap[4];
    #pragma unroll
    for (int m = 0; m < 4; ++m)
      ap[m] = adj + (size_t)(b * DD + i0 + rbase + mb0 + m) * DD + l * 64;
    unsigned lo[4] = {0u, 0u, 0u, 0u}, hi[4] = {0u, 0u, 0u, 0u};

    auto p1_load = [&](i32x4 (&buf)[4][2], int q) {
      #pragma unroll
      for (int m = 0; m < 4; ++m) {
        buf[m][0] = *(const i32x4*)(ap[m] + q * 8);
        buf[m][1] = *(const i32x4*)(ap[m] + q * 8 + 4);
      }
    };
    auto p1_cons = [&](i32x4 (&buf)[4][2], int q) {
      #pragma unroll
      for (int u = 0; u < 2; ++u) {
        const int o = q * 8 + u * 4;
        float4 f = *(const float4*)(ftl + o);
        #pragma unroll
        for (int m = 0; m < 4; ++m) {
          i32x4 a = buf[m][u];
          float e;
          e = fsr[mb0+m] + f.x; e = fmaxf(e, SLOPE * e); e = a.x ? e : 0.f; sum[mb0+m] += __expf(e - Mr[mb0+m]);
          e = fsr[mb0+m] + f.y; e = fmaxf(e, SLOPE * e); e = a.y ? e : 0.f; sum[mb0+m] += __expf(e - Mr[mb0+m]);
          e = fsr[mb0+m] + f.z; e = fmaxf(e, SLOPE * e); e = a.z ? e : 0.f; sum[mb0+m] += __expf(e - Mr[mb0+m]);
          e = fsr[mb0+m] + f.w; e = fmaxf(e, SLOPE * e); e = a.w ? e : 0.f; sum[mb0+m] += __expf(e - Mr[mb0+m]);
          unsigned pack = (a.x ? 1u : 0u) | (a.y ? 2u : 0u) | (a.z ? 4u : 0u) | (a.w ? 8u : 0u);
          if (o < 32) lo[m] |= pack << o; else hi[m] |= pack << (o - 32);
        }
      }
    };

    i32x4 bA[4][2], bB[4][2];
    p1_load(bA, 0);
    p1_load(bB, 1);
    #pragma unroll
    for (int q = 0; q < 8; q += 2) {
      p1_cons(bA, q);
      if (q + 2 < 8) p1_load(bA, q + 2);
      p1_cons(bB, q + 1);
      if (q + 3 < 8) p1_load(bB, q + 3);
    }
    #pragma unroll
    for (int m = 0; m < 4; ++m) {
      uint2 mv; mv.x = lo[m]; mv.y = hi[m];
      *(uint2*)&mlds[(rbase + mb0 + m) * 128 + l * 2] = mv;
    }
  }
  #pragma unroll
  for (int m = 0; m < 8; ++m) {
    #pragma unroll
    for (int s = 1; s < 64; s <<= 1) sum[m] += __shfl_xor(sum[m], s);
    inv[m] = 1.0f / sum[m];
  }

  // ---- Pass 2: 16-chunk pipeline (soft barriers, B/ft double-buffered) ----
  const float* ftb = ft + (size_t)b * DD;
  float* arow[8];
  unsigned o_[8], wb_[8];
  const int jl = l * 4;
  const unsigned mshift = (unsigned)(jl & 31);
  #pragma unroll
  for (int m = 0; m < 8; ++m) {
    const int r = rbase + m;
    arow[m] = attn + (size_t)b * DD * DD + (size_t)(i0 + r) * DD;
    o_[m] = (((unsigned)r * 512u) + (unsigned)jl * 2u) ^ ((unsigned)(r & 7) << 4);
    wb_[m] = (unsigned)r * 128u + (unsigned)(jl >> 5);
  }
  const int f0 = w * 16;
  const int c15 = l & 15;
  const int kg = l >> 4;
  const unsigned abase = (unsigned)c15 * 512u + (unsigned)kg * 16u;
  const unsigned asw = (unsigned)(c15 & 7) << 4;
  const unsigned short* wrow = WhT + ((size_t)b * FF + f0 + c15) * DD + kg * 8;
  f32x4 acc[4];
  #pragma unroll
  for (int q = 0; q < 4; ++q) acc[q] = (f32x4){0.f, 0.f, 0.f, 0.f};

  bf16x8 BvA[8], BvB[8];
  float4 fA, fB;
  #pragma unroll
  for (int u = 0; u < 8; ++u)
    BvA[u] = *(const bf16x8*)&wrow[(size_t)u * 32];
  fA = *(const float4*)(ftb + jl);

#define CHUNK_BODY(CC, BCUR, BNXT, FCUR, FNXT) do { \
    const int c_ = (CC); \
    const int j_ = c_ * 256 + jl; \
    /* issue next chunk's B and ft early: in flight across soft barrier */ \
    _Pragma("unroll") \
    for (int u = 0; u < 8; ++u) \
      BNXT[u] = *(const bf16x8*)&wrow[(size_t)((((c_) + 1) & 15) * 8 + u) * 32]; \
    FNXT = *(const float4*)(ftb + ((((c_) + 1) & 15) * 256 + jl)); \
    float4 f4_ = FCUR; \
    f32x4 v_[8]; \
    _Pragma("unroll") \
    for (int m = 0; m < 8; ++m) { \
      unsigned n_ = (mlds[wb_[m] + (unsigned)c_ * 8u] >> mshift) & 0xFu; \
      float e_, p0_, p1_, p2_, p3_; \
      e_ = fsr[m] + f4_.x; e_ = fmaxf(e_, SLOPE * e_); e_ = (n_ & 1u) ? e_ : 0.f; p0_ = __expf(e_ - Mr[m]) * inv[m]; \
      e_ = fsr[m] + f4_.y; e_ = fmaxf(e_, SLOPE * e_); e_ = (n_ & 2u) ? e_ : 0.f; p1_ = __expf(e_ - Mr[m]) * inv[m]; \
      e_ = fsr[m] + f4_.z; e_ = fmaxf(e_, SLOPE * e_); e_ = (n_ & 4u) ? e_ : 0.f; p2_ = __expf(e_ - Mr[m]) * inv[m]; \
      e_ = fsr[m] + f4_.w; e_ = fmaxf(e_, SLOPE * e_); e_ = (n_ & 8u) ? e_ : 0.f; p3_ = __expf(e_ - Mr[m]) * inv[m]; \
      v_[m].x = p0_; v_[m].y = p1_; v_[m].z = p2_; v_[m].w = p3_; \
      ushort4 qv_; qv_.x = f2bf(p0_); qv_.y = f2bf(p1_); qv_.z = f2bf(p2_); qv_.w = f2bf(p3_); \
      *(ushort4*)((char*)&p_lds[c_ & 1][0] + o_[m]) = qv_; \
    } \
    SOFT_BARRIER(); \
    /* attn stores AFTER barrier: off the gating path, overlap MFMA */ \
    _Pragma("unroll") \
    for (int m = 0; m < 8; ++m) \
      *(f32x4*)(arow[m] + j_) = v_[m]; \
    __builtin_amdgcn_s_setprio(1); \
    _Pragma("unroll") \
    for (int u = 0; u < 8; ++u) { \
      unsigned ao_ = (abase + (unsigned)u * 64u) ^ asw; \
      _Pragma("unroll") \
      for (int T = 0; T < 4; ++T) { \
        bf16x8 A_ = *(const bf16x8*)((const char*)&p_lds[c_ & 1][0] + ao_ + (unsigned)T * 8192u); \
        acc[T] = __builtin_amdgcn_mfma_f32_16x16x32_bf16(A_, BCUR[u], acc[T], 0, 0, 0); \
      } \
    } \
    __builtin_amdgcn_s_setprio(0); \
  } while (0)

  for (int cc = 0; cc < 8; ++cc) {
    CHUNK_BODY(cc * 2,     BvA, BvB, fA, fB);
    CHUNK_BODY(cc * 2 + 1, BvB, BvA, fB, fA);
  }
#undef CHUNK_BODY

  const float bv = bias[f0 + c15];
  #pragma unroll
  for (int T = 0; T < 4; ++T) {
    #pragma unroll
    for (int q = 0; q < 4; ++q) {
      int orow = T * 16 + kg * 4 + q;   // C/D: row = (lane>>4)*4 + reg
      hout[((size_t)b * DD + i0 + orow) * FF + f0 + c15] = acc[T][q] + bv;
    }
  }
}

extern "C" void kernel_launch(void* const* d_in, const int* in_sizes, int n_in,
                              void* d_out, int out_size, void* d_ws, size_t ws_size,
                              hipStream_t stream) {
  const float* x     = (const float*)d_in[0];
  const int*   adj   = (const int*)d_in[1];
  const float* W     = (const float*)d_in[2];
  const float* a_src = (const float*)d_in[3];
  const float* a_tgt = (const float*)d_in[4];
  const float* bias  = (const float*)d_in[5];
  char* ws = (char*)d_ws;
  unsigned short* WhT    = (unsigned short*)ws;         // 4 MB
  float*        fs     = (float*)(ws + 4194304);        // 64 KB
  float*        ft     = (float*)(ws + 4259840);        // 64 KB
  float*        mbpart = (float*)(ws + 4325376);        // 1 KB
  float* hout = (float*)d_out;                          // [B][D][F]
  float* attn = hout + (size_t)BB * DD * FF;            // [B][D][D]
  kA<<<256, 256, 0, stream>>>(x, W, a_src, a_tgt, WhT, fs, ft, mbpart);
  kF<<<256, 512, 0, stream>>>(adj, fs, ft, mbpart, WhT, bias, hout, attn);
}